// Round 5
// baseline (178.209 us; speedup 1.0000x reference)
//
#include <hip/hip_runtime.h>
#include <hip/hip_bf16.h>
#include <cstdint>

// ---------------------------------------------------------------------------
// SingleDeformConv on MI355X (gfx950)
// data (8,64,128,128) f32; w (64,64,3,3); b (64); w_off (18,64,3,3); b_off(18);
// w_mod (9,64,3,3); b_mod (9).  out = relu(deform_conv(...)) (8,64,128,128) f32
//
// R4 -> R5: 4 kernels -> 2.
//  * conv27 fused INTO deform_main: per-block 3x66x64ch halo tile -> 27-ch
//    conv MFMA -> convOut in LDS -> phase-0 builds gather params from LDS.
//    offP global round-trip (28 MB) and one launch eliminated. LDS regions
//    overlap (halo dead after conv MFMAs): total 46.9 KB, 3 blocks/CU.
//  * pack_weights merged into transpose (single prep kernel).
// ---------------------------------------------------------------------------

typedef __attribute__((ext_vector_type(8))) short short8;
typedef __attribute__((ext_vector_type(4))) float floatx4;
typedef __attribute__((ext_vector_type(2))) float floatx2;

__device__ __forceinline__ unsigned short f2bf(float x) {
    unsigned int u = __float_as_uint(x);
    u += 0x7fffu + ((u >> 16) & 1u);           // round-to-nearest-even
    return (unsigned short)(u >> 16);
}
// pack two floats -> bf16x2 dword (RNE)
__device__ __forceinline__ unsigned int pack2bf(float lo, float hi) {
    unsigned int ul = __float_as_uint(lo); ul += 0x7fffu + ((ul >> 16) & 1u);
    unsigned int uh = __float_as_uint(hi); uh += 0x7fffu + ((uh >> 16) & 1u);
    return __builtin_amdgcn_perm(uh, ul, 0x07060302u);  // [lo.b2,lo.b3,hi.b2,hi.b3]
}
// unpack bf16x2 dword -> float2 (lo, hi)
__device__ __forceinline__ floatx2 up2(unsigned int u) {
    floatx2 r;
    r.x = __uint_as_float(u << 16);
    r.y = __uint_as_float(u & 0xffff0000u);
    return r;
}
// blend one bf16x2 dword from 4 corners with weights fw -> packed bf16x2
__device__ __forceinline__ unsigned int blend2pk(unsigned int a, unsigned int b,
                                                 unsigned int c, unsigned int d,
                                                 float4 fw) {
    floatx2 s = up2(a) * fw.x;
    s += up2(b) * fw.y;
    s += up2(c) * fw.z;
    s += up2(d) * fw.w;
    __hip_bfloat162 h = __float22bfloat162_rn(make_float2(s.x, s.y));
    return *(unsigned int*)&h;
}

// Workspace layout (bytes)
#define OFF_DATAT 0u               // [8][16384][64] bf16  = 16777216 B
#define OFF_WM    16777216u        // [64][576] bf16       = 73728 B
#define OFF_W27   16850944u        // [32][576] bf16       = 36864 B
// total 16887808 B

// ---------------------------------------------------------------------------
// Kernel 1: prep = NCHW f32 -> NHWC bf16 transpose (blocks 0..2047)
//           + weight packing, K index = k*64 + c (blocks 2048..2263)
// ---------------------------------------------------------------------------
__global__ __launch_bounds__(256) void prep_k(const float* __restrict__ x,
                                              unsigned short* __restrict__ xt,
                                              const float* __restrict__ w,
                                              const float* __restrict__ w_off,
                                              const float* __restrict__ w_mod,
                                              unsigned short* __restrict__ wpackM,
                                              unsigned short* __restrict__ wpack27) {
    __shared__ float tile[64][65];                 // +1 pad: conflict-free transpose
    int blk = blockIdx.x;
    if (blk < 2048) {                              // ---- transpose ----
        int b    = blk >> 8;
        int pos0 = (blk & 255) << 6;
        int lane = threadIdx.x & 63;
        int g    = threadIdx.x >> 6;
        for (int c = g; c < 64; c += 4)
            tile[c][lane] = x[(((b << 6) + c) << 14) + pos0 + lane];   // coalesced
        __syncthreads();
        int c2 = lane & 31;
        for (int i = g; i < 32; i += 4) {          // dword-packed stores
            int pr = (i << 1) + (lane >> 5);
            unsigned int d = pack2bf(tile[c2 << 1][pr], tile[(c2 << 1) + 1][pr]);
            *(unsigned int*)&xt[((size_t)((b << 14) + pos0 + pr) << 6) + (c2 << 1)] = d;
        }
        return;
    }
    // ---- weight packing ----
    int t = (blk - 2048) * 256 + threadIdx.x;
    if (t < 64 * 576) {
        int o = t / 576, kk = t % 576;
        int k = kk >> 6, c = kk & 63;
        wpackM[t] = f2bf(w[(o * 64 + c) * 9 + k]);
        return;
    }
    t -= 64 * 576;
    if (t < 32 * 576) {
        int o = t / 576, kk = t % 576;
        int k = kk >> 6, c = kk & 63;
        float v = 0.f;
        if (o < 18)      v = w_off[(o * 64 + c) * 9 + k];
        else if (o < 27) v = w_mod[((o - 18) * 64 + c) * 9 + k];
        wpack27[t] = f2bf(v);
    }
}

// ---------------------------------------------------------------------------
// Kernel 2: fused offset-conv + deformable conv. Block: 256 thr (4 waves),
// 64 positions (one row-half: y = blk>>1 & 127... see mapping).
// Phase A: stage 3x66x64ch bf16 halo -> 27-ch conv MFMA -> convOut LDS.
// Phase B: phase-0 gather params (from convOut + biases, sigmoid) -> pOff/pW.
// Phase C: R4's pipelined gather/blend/MFMA over 9 taps, double-buffered samp.
// LDS: union{ halo 28512 | convOut 8192 + samp 18432 } + pOff/pW 18432.
// ---------------------------------------------------------------------------
__global__ __launch_bounds__(256) void deform_fused_k(const unsigned short* __restrict__ xt,
                                                      const unsigned short* __restrict__ wpackM,
                                                      const unsigned short* __restrict__ wpack27,
                                                      const float* __restrict__ b_off,
                                                      const float* __restrict__ b_mod,
                                                      const float* __restrict__ bias,
                                                      float* __restrict__ out) {
    __shared__ union {
        unsigned short halo[3][66][72];            // 28512 B (phase A)
        struct {
            float convOut[32][64];                 // 8192 B  (phase A out / B in)
            unsigned short samp[2][64][72];        // 18432 B (phase C)
        } s2;
    } U;
    __shared__ int4   pOff[576];                   // 9216 B
    __shared__ float4 pW[576];                     // 9216 B

    int blk  = blockIdx.x;                         // 2048 = 8 b * 256
    int b    = blk >> 8;
    int pos0 = (blk & 255) << 6;
    int y    = (blk & 255) >> 1;                   // image row of this block
    int h    = blk & 1;                            // column half
    int tid  = threadIdx.x;
    int lane = tid & 63, wv = tid >> 6;
    int r = lane & 15, q = lane >> 4;
    int pg = lane >> 3;                            // position subgroup 0..7
    int j8 = lane & 7;                             // channel chunk (8 bf16 = 16B)

    const unsigned short* xb  = xt + ((size_t)b << 20);   // b*16384*64
    const char*           xbb = (const char*)xb;

    // ======== Phase A: halo stage + 27-ch conv ========
    {
        int g = tid >> 3, j = tid & 7;             // 32 col-groups, 8 ch-chunks
        #pragma unroll
        for (int rr = 0; rr < 3; ++rr) {
            int sy = y + rr - 1;
            #pragma unroll
            for (int ci = 0; ci < 3; ++ci) {
                int col = g + (ci << 5);
                if (col < 66) {
                    int sx = (h << 6) + col - 1;
                    uint4 v = {0u, 0u, 0u, 0u};
                    if (sy >= 0 && sy < 128 && sx >= 0 && sx < 128)
                        v = *(const uint4*)&xb[(size_t)(((sy << 7) + sx) << 6) + (j << 3)];
                    *(uint4*)&U.halo[rr][col][j << 3] = v;
                }
            }
        }
    }
    __syncthreads();

    {
        int i_oc = wv >> 1, j_pos = wv & 1;        // 2 oc-strips x 2 pos-halves
        floatx4 acc2[2] = {};
        #pragma unroll
        for (int k = 0; k < 9; ++k) {
            int ki = k / 3, kj = k % 3;
            #pragma unroll
            for (int ch = 0; ch < 2; ++ch) {
                short8 a = *(const short8*)&wpack27[((i_oc << 4) + r) * 576 + (k << 6) + (ch << 5) + (q << 3)];
                #pragma unroll
                for (int nt = 0; nt < 2; ++nt) {
                    int col = (j_pos << 5) + (nt << 4) + r + kj;   // <= 65
                    short8 bf = *(const short8*)&U.halo[ki][col][(ch << 5) + (q << 3)];
                    acc2[nt] = __builtin_amdgcn_mfma_f32_16x16x32_bf16(a, bf, acc2[nt], 0, 0, 0);
                }
            }
        }
        __syncthreads();                           // all halo reads complete
        #pragma unroll
        for (int nt = 0; nt < 2; ++nt) {
            #pragma unroll
            for (int reg = 0; reg < 4; ++reg) {
                int oc  = (i_oc << 4) + (q << 2) + reg;
                int pl  = (j_pos << 5) + (nt << 4) + r;
                U.s2.convOut[oc][pl] = acc2[nt][reg];
            }
        }
    }
    __syncthreads();                               // convOut visible

    // ======== Phase B: gather params ========
    for (int e = tid; e < 576; e += 256) {
        int k = e >> 6, p = e & 63;
        int pos = pos0 + p;
        float dy = U.s2.convOut[(k << 1)][p]     + b_off[(k << 1)];
        float dx = U.s2.convOut[(k << 1) + 1][p] + b_off[(k << 1) + 1];
        float mm = U.s2.convOut[18 + k][p]       + b_mod[k];
        float m  = 2.f / (1.f + __expf(-mm));
        float py = (float)(pos >> 7) + (float)(k / 3 - 1) + dy;
        float px = (float)(pos & 127) + (float)(k % 3 - 1) + dx;
        float y0f = floorf(py), x0f = floorf(px);
        int y0 = (int)y0f, x0 = (int)x0f;
        float wy1 = py - y0f, wx1 = px - x0f;
        float wy0 = 1.f - wy1, wx0 = 1.f - wx1;
        bool vy0 = (y0 >= 0) && (y0 < 128);
        bool vy1 = (y0 >= -1) && (y0 < 127);
        bool vx0 = (x0 >= 0) && (x0 < 128);
        bool vx1 = (x0 >= -1) && (x0 < 127);
        float w00 = (vy0 && vx0) ? m * wy0 * wx0 : 0.f;
        float w01 = (vy0 && vx1) ? m * wy0 * wx1 : 0.f;
        float w10 = (vy1 && vx0) ? m * wy1 * wx0 : 0.f;
        float w11 = (vy1 && vx1) ? m * wy1 * wx1 : 0.f;
        int y0c = min(max(y0, 0), 127), y1c = min(max(y0 + 1, 0), 127);
        int x0c = min(max(x0, 0), 127), x1c = min(max(x0 + 1, 0), 127);
        pOff[e] = make_int4(((y0c << 7) + x0c) << 7, ((y0c << 7) + x1c) << 7,
                            ((y1c << 7) + x0c) << 7, ((y1c << 7) + x1c) << 7);
        pW[e] = make_float4(w00, w01, w10, w11);
    }
    __syncthreads();                               // pOff/pW ready, halo dead

    // ======== Phase C: pipelined gather + MFMA ========
    floatx4 acc[4] = {};
    const char* xp = xbb + (j8 << 4);              // per-lane channel-chunk base
    const unsigned short* wrow = wpackM + ((wv << 4) + r) * 576 + (q << 3);

    uint4  c00[2], c01[2], c10[2], c11[2];         // prefetched corners
    float4 cw[2];
    short8 afC[2], afN[2];                         // A-frags, current / next

    auto issue = [&](int k) {
        #pragma unroll
        for (int i = 0; i < 2; ++i) {
            int e  = (k << 6) + (wv << 4) + (i << 3) + pg;
            int4   io = pOff[e];
            cw[i]  = pW[e];
            c00[i] = *(const uint4*)(xp + io.x);
            c01[i] = *(const uint4*)(xp + io.y);
            c10[i] = *(const uint4*)(xp + io.z);
            c11[i] = *(const uint4*)(xp + io.w);
        }
    };
    auto blendStore = [&](int buf) {
        #pragma unroll
        for (int i = 0; i < 2; ++i) {
            int p = (wv << 4) + (i << 3) + pg;
            uint4 o4;
            o4.x = blend2pk(c00[i].x, c01[i].x, c10[i].x, c11[i].x, cw[i]);
            o4.y = blend2pk(c00[i].y, c01[i].y, c10[i].y, c11[i].y, cw[i]);
            o4.z = blend2pk(c00[i].z, c01[i].z, c10[i].z, c11[i].z, cw[i]);
            o4.w = blend2pk(c00[i].w, c01[i].w, c10[i].w, c11[i].w, cw[i]);
            *(uint4*)&U.s2.samp[buf][p][j8 << 3] = o4;
        }
    };

    issue(0);
    afC[0] = *(const short8*)&wrow[0];
    afC[1] = *(const short8*)&wrow[32];
    blendStore(0);

    for (int k = 0; k < 9; ++k) {
        if (k < 8) {
            issue(k + 1);                          // VMEM in flight across barrier
            afN[0] = *(const short8*)&wrow[((k + 1) << 6)];
            afN[1] = *(const short8*)&wrow[((k + 1) << 6) + 32];
        }
        __syncthreads();                           // samp[k&1] complete block-wide
        #pragma unroll
        for (int ch = 0; ch < 2; ++ch) {
            #pragma unroll
            for (int nt = 0; nt < 4; ++nt) {
                short8 bfrag = *(const short8*)&U.s2.samp[k & 1][(nt << 4) + r][(ch << 5) + (q << 3)];
                acc[nt] = __builtin_amdgcn_mfma_f32_16x16x32_bf16(afC[ch], bfrag, acc[nt], 0, 0, 0);
            }
        }
        if (k < 8) {
            blendStore((k + 1) & 1);
            afC[0] = afN[0];
            afC[1] = afN[1];
        }
    }

    #pragma unroll
    for (int nt = 0; nt < 4; ++nt) {
        #pragma unroll
        for (int reg = 0; reg < 4; ++reg) {
            int oc  = (wv << 4) + (q << 2) + reg;
            int pos = pos0 + (nt << 4) + r;
            float v = acc[nt][reg] + bias[oc];
            out[(size_t)(((b << 6) + oc) << 14) + pos] = fmaxf(v, 0.f);
        }
    }
}

// ---------------------------------------------------------------------------
extern "C" void kernel_launch(void* const* d_in, const int* in_sizes, int n_in,
                              void* d_out, int out_size, void* d_ws, size_t ws_size,
                              hipStream_t stream) {
    const float* data  = (const float*)d_in[0];
    const float* w     = (const float*)d_in[1];
    const float* bias  = (const float*)d_in[2];
    const float* w_off = (const float*)d_in[3];
    const float* b_off = (const float*)d_in[4];
    const float* w_mod = (const float*)d_in[5];
    const float* b_mod = (const float*)d_in[6];
    float* out = (float*)d_out;

    char* ws = (char*)d_ws;
    unsigned short* dataT   = (unsigned short*)(ws + OFF_DATAT);
    unsigned short* wpackM  = (unsigned short*)(ws + OFF_WM);
    unsigned short* wpack27 = (unsigned short*)(ws + OFF_W27);

    prep_k<<<2264, 256, 0, stream>>>(data, dataT, w, w_off, w_mod, wpackM, wpack27);
    deform_fused_k<<<2048, 256, 0, stream>>>(dataT, wpackM, wpack27,
                                             b_off, b_mod, bias, out);
}